// Round 9
// baseline (1731.010 us; speedup 1.0000x reference)
//
#include <hip/hip_runtime.h>
#include <cstddef>

#define SCALE (1.0f/16.0f)

__device__ __forceinline__ float hatG(float t){
  float tl = fminf(fmaxf(t,-1.f),0.f);
  float tr = fminf(fmaxf(t,0.f),1.f);
  return 0.5f*(tl+1.f)*(tl+1.f) + 0.5f - 0.5f*(1.f-tr)*(1.f-tr);
}

// dst[c*ldd + off + r] = src[r*cols + c]; batched via blockIdx.z
__global__ __launch_bounds__(256) void k_transpose(const float* __restrict__ src,
    float* __restrict__ dst, int rows, int cols, int ldd, int off){
  __shared__ float tile[32][33];
  src += (size_t)blockIdx.z * rows * cols;
  dst += (size_t)blockIdx.z * cols * ldd;
  int c0 = blockIdx.x*32, r0 = blockIdx.y*32;
  int tx = threadIdx.x, ty = threadIdx.y;
  for(int i=ty;i<32;i+=8){
    int r=r0+i, c=c0+tx;
    if(r<rows && c<cols) tile[i][tx] = src[(size_t)r*cols + c];
  }
  __syncthreads();
  for(int i=ty;i<32;i+=8){
    int c=c0+i, r=r0+tx;
    if(c<cols && r<rows) dst[(size_t)c*ldd + off + r] = tile[tx][i];
  }
}

__global__ void k_bias640(const float* __restrict__ a, const float* __restrict__ b,
                          float* __restrict__ o){
  int i = threadIdx.x + blockIdx.x*256;
  if(i<256) o[i]=a[i];
  else if(i<640) o[i]=b[i-256];
}

__device__ void imap_one(float ix1,float iy1,float ix2,float iy2,
                         float ax1,float ay1,float ax2,float ay2,
                         float* __restrict__ out){
  float ch = fmaxf((ay2-ay1)/7.f, 1e-9f);
  float cw = fmaxf((ax2-ax1)/7.f, 1e-9f);
  float oy[7], ox[7];
  #pragma unroll
  for(int p=0;p<7;p++){
    float e0 = ay1 + (ay2-ay1)*((float)p/7.f);
    float e1 = ay1 + (ay2-ay1)*((float)(p+1)/7.f);
    oy[p] = fmaxf(fminf(e1, iy2) - fmaxf(e0, iy1), 0.f) / ch;
  }
  #pragma unroll
  for(int q=0;q<7;q++){
    float e0 = ax1 + (ax2-ax1)*((float)q/7.f);
    float e1 = ax1 + (ax2-ax1)*((float)(q+1)/7.f);
    ox[q] = fmaxf(fminf(e1, ix2) - fmaxf(e0, ix1), 0.f) / cw;
  }
  for(int p=0;p<7;p++)
    for(int q=0;q<7;q++) out[p*7+q] = oy[p]*ox[q];
}

__global__ __launch_bounds__(256) void k_imap(const float* __restrict__ boxes,
  float* __restrict__ unions, float* __restrict__ boximap,
  float* __restrict__ subimap, float* __restrict__ objimap){
  int b = blockIdx.x, m = threadIdx.x;
  const float* bx = boxes + (size_t)b*16*4;
  int i = m>>4, j = m&15;              // sub = repeat -> i, obj = tile -> j
  float sx1=bx[i*4+0], sy1=bx[i*4+1], sx2=bx[i*4+2], sy2=bx[i*4+3];
  float ox1=bx[j*4+0], oy1=bx[j*4+1], ox2=bx[j*4+2], oy2=bx[j*4+3];
  float ux1=fminf(sx1,ox1), uy1=fminf(sy1,oy1);
  float ux2=fmaxf(sx2,ox2), uy2=fmaxf(sy2,oy2);
  float* up = unions + ((size_t)b*256+m)*4;
  up[0]=ux1; up[1]=uy1; up[2]=ux2; up[3]=uy2;
  imap_one(sx1,sy1,sx2,sy2, ux1,uy1,ux2,uy2, subimap + ((size_t)b*256+m)*49);
  imap_one(ox1,oy1,ox2,oy2, ux1,uy1,ux2,uy2, objimap + ((size_t)b*256+m)*49);
  if(m<16){
    imap_one(bx[m*4+0],bx[m*4+1],bx[m*4+2],bx[m*4+3],
             0.f,0.f,384.f,256.f, boximap + ((size_t)b*16+m)*49);
  }
}

// PrRoI bin weights in SCALED feature coords (box already * SCALE).
__device__ __forceinline__ void build_weights(int tid, float x1s,float y1s,float x2s,float y2s,
                              float (*wxs)[24], float (*wys)[16]){
  if(tid<7){
    int q=tid;
    float e0 = x1s + (x2s-x1s)*((float)q/7.f);
    float e1 = x1s + (x2s-x1s)*((float)(q+1)/7.f);
    for(int i2=0;i2<24;i2++) wxs[q][i2] = hatG(e1-(float)i2)-hatG(e0-(float)i2);
  } else if(tid>=16 && tid<23){
    int p=tid-16;
    float e0 = y1s + (y2s-y1s)*((float)p/7.f);
    float e1 = y1s + (y2s-y1s)*((float)(p+1)/7.f);
    for(int i2=0;i2<16;i2++) wys[p][i2] = hatG(e1-(float)i2)-hatG(e0-(float)i2);
  }
}

// Pool ctx channels (0..255 of feats2T) with the full-image box -> ctxpool[b][s][c]
__global__ __launch_bounds__(256) void k_ctxpool(const float* __restrict__ feats2T,
                                                 float* __restrict__ ctxpool){
  __shared__ float wxs[7][24];
  __shared__ float wys[7][16];
  int b = blockIdx.x, tid = threadIdx.x;
  build_weights(tid, 0.f, 0.f, 24.f, 16.f, wxs, wys);
  __syncthreads();
  int c = tid;
  const float* f = feats2T + (size_t)b*384*640 + c;
  float invA = 49.f/(24.f*16.f);
  for(int p=0;p<7;p++){
    float tyv[24];
    #pragma unroll
    for(int w=0;w<24;w++) tyv[w]=0.f;
    for(int h=0;h<16;h++){
      float wv = wys[p][h];
      if(wv==0.f) continue;
      const float* fr = f + (size_t)(h*24)*640;
      #pragma unroll
      for(int w=0;w<24;w++) tyv[w] += wv*fr[(size_t)w*640];
    }
    for(int q=0;q<7;q++){
      float s=0.f;
      #pragma unroll
      for(int w=0;w<24;w++) s += wxs[q][w]*tyv[w];
      ctxpool[((size_t)b*49 + p*7+q)*256 + c] = s*invA;
    }
  }
}

// Pool feat with obj boxes, write fused-input rows: inbuf[b][n][s][c512]
__global__ __launch_bounds__(256) void k_objpool(const float* __restrict__ boxes,
    const float* __restrict__ featT, const float* __restrict__ ctxpool,
    const float* __restrict__ boximap, float* __restrict__ inbuf){
  __shared__ float wxs[7][24];
  __shared__ float wys[7][16];
  int blk = blockIdx.x; int b = blk>>4, n = blk&15; int tid = threadIdx.x;
  const float* bx = boxes + ((size_t)b*16+n)*4;
  float x1s=bx[0]*SCALE, y1s=bx[1]*SCALE, x2s=bx[2]*SCALE, y2s=bx[3]*SCALE;
  build_weights(tid, x1s,y1s,x2s,y2s, wxs, wys);
  __syncthreads();
  float area = (x2s-x1s)*(y2s-y1s)/49.f;
  float sc = area>0.f ? 1.f/fmaxf(area,1e-9f) : 0.f;
  int c = tid;
  const float* f = featT + (size_t)b*384*256 + c;
  float* ob = inbuf + (size_t)(b*16+n)*49*512;
  for(int p=0;p<7;p++){
    float tyv[24];
    #pragma unroll
    for(int w=0;w<24;w++) tyv[w]=0.f;
    for(int h=0;h<16;h++){
      float wv = wys[p][h];
      if(wv==0.f) continue;
      const float* fr = f + (size_t)(h*24)*256;
      #pragma unroll
      for(int w=0;w<24;w++) tyv[w] += wv*fr[(size_t)w*256];
    }
    for(int q=0;q<7;q++){
      float s=0.f;
      #pragma unroll
      for(int w=0;w<24;w++) s += wxs[q][w]*tyv[w];
      ob[(size_t)(p*7+q)*512 + c] = s*sc;
    }
  }
  // concat channels 256..511: x (ctx 0..127), y*box_imap (ctx 128..255)
  const float* cp = ctxpool + (size_t)b*49*256;
  for(int s=0;s<49;s++){
    float bi = boximap[((size_t)b*16+n)*49 + s];
    if(tid<128) ob[(size_t)s*512 + 256 + tid] = cp[(size_t)s*256 + tid];
    else        ob[(size_t)s*512 + 384 + (tid-128)] = cp[(size_t)s*256 + 128 + (tid-128)] * bi;
  }
}

// Tiled fp32 GEMM: C[M,N] = A[M,K] * B[K,N] (+bias). flags: 1=reluA, 2=permB.
// grid.z batches (aZ/cZ strides) and doubles as split-K / B-row-window (kBasePerZ).
// 256 threads. Requires M%BM==0, N%BN==0, Kchunk%32==0, float4 alignment.
template<int BM,int BN,int TM,int TN>
__global__ __launch_bounds__(256) void k_gemm(
    const float* __restrict__ A, int lda, long long aZ,
    const float* __restrict__ B, int ldb,
    const float* __restrict__ bias,
    float* __restrict__ C, int ldc, long long cZ,
    int Kchunk, int kBasePerZ, int flags)
{
  static_assert((BM/TM)*(BN/TN)==256 && BN/TN==16, "layout");
  int z = blockIdx.z;
  A += (size_t)z*aZ; C += (size_t)z*cZ;
  int kBase = z*kBasePerZ;
  int m0 = blockIdx.y*BM, n0 = blockIdx.x*BN;
  __shared__ float As[32][BM];
  __shared__ float Bs[32][BN];
  int tid = threadIdx.x, tx = tid&15, ty = tid>>4;
  float acc[TM][TN] = {};
  constexpr int AV = BM/32;          // float4s per thread for A stage
  constexpr int NB4 = BN/4;          // float4 columns in B stage
  constexpr int KSTEP = 256/NB4;     // k-rows stride in B stage
  constexpr int TM4 = TM/4, TN4 = TN/4;
  for(int k0=0;k0<Kchunk;k0+=32){
    {
      int m = tid % BM; int kk0 = (tid / BM) * (AV*4);
      const float* ap = A + (size_t)(m0+m)*lda + (k0+kk0);
      #pragma unroll
      for(int v=0;v<AV;v++){
        float4 x = *(const float4*)(ap + v*4);
        if(flags&1){
          x.x=fmaxf(x.x,0.f); x.y=fmaxf(x.y,0.f); x.z=fmaxf(x.z,0.f); x.w=fmaxf(x.w,0.f);
        }
        As[kk0+v*4+0][m]=x.x; As[kk0+v*4+1][m]=x.y;
        As[kk0+v*4+2][m]=x.z; As[kk0+v*4+3][m]=x.w;
      }
    }
    {
      int n4 = (tid % NB4)*4; int kr = tid / NB4;
      #pragma unroll
      for(int kk=kr; kk<32; kk+=KSTEP){
        int kg = kBase + k0 + kk;
        int src = (flags&2) ? ((kg&255)*49 + (kg>>8)) : kg;  // K perm: ours s*256+c -> ref c*49+s
        *(float4*)&Bs[kk][n4] = *(const float4*)(B + (size_t)src*ldb + n0 + n4);
      }
    }
    __syncthreads();
    #pragma unroll
    for(int kk=0;kk<32;kk++){
      float av[TM], bvv[TN];
      #pragma unroll
      for(int v=0;v<TM4;v++) *(float4*)&av[v*4]  = *(const float4*)&As[kk][ty*TM + v*4];
      #pragma unroll
      for(int u=0;u<TN4;u++) *(float4*)&bvv[u*4] = *(const float4*)&Bs[kk][tx*4 + u*64];
      #pragma unroll
      for(int i=0;i<TM;i++)
        #pragma unroll
        for(int j=0;j<TN;j++) acc[i][j] += av[i]*bvv[j];
    }
    __syncthreads();
  }
  float bb[TN];
  #pragma unroll
  for(int u=0;u<TN4;u++){
    float4 v = make_float4(0.f,0.f,0.f,0.f);
    if(bias) v = *(const float4*)(bias + n0 + tx*4 + u*64);
    bb[u*4+0]=v.x; bb[u*4+1]=v.y; bb[u*4+2]=v.z; bb[u*4+3]=v.w;
  }
  #pragma unroll
  for(int r=0;r<TM;r++){
    #pragma unroll
    for(int u=0;u<TN4;u++){
      float4 o;
      o.x = acc[r][u*4+0]+bb[u*4+0]; o.y = acc[r][u*4+1]+bb[u*4+1];
      o.z = acc[r][u*4+2]+bb[u*4+2]; o.w = acc[r][u*4+3]+bb[u*4+3];
      *(float4*)(C + (size_t)(m0+ty*TM+r)*ldc + n0 + tx*4 + u*64) = o;
    }
  }
}

// Per-pair prroi-pool of rel_feat over union box, modulated by imaps, written
// as GEMM-ready rows: pairA[(lp*49+s)*384 + c] for lp in this chunk.
__global__ __launch_bounds__(384) void k_poolpairs(
  const float* __restrict__ feats2T, const float* __restrict__ unions,
  const float* __restrict__ subimap, const float* __restrict__ objimap,
  float* __restrict__ pairA, int P0)
{
  __shared__ float wxs[7][24];
  __shared__ float wys[7][16];
  __shared__ float subm[49];
  __shared__ float objm[49];
  __shared__ int hmaskS[16];            // any wys[p][h] != 0
  __shared__ int cmaskS[8];             // any wxs[q][wc*4..wc*4+3] != 0
  int lp = blockIdx.x; int gp = P0 + lp; int b = gp>>8; int tid = threadIdx.x;
  const float* u = unions + (size_t)gp*4;
  float x1s=u[0]*SCALE, y1s=u[1]*SCALE, x2s=u[2]*SCALE, y2s=u[3]*SCALE;
  build_weights(tid, x1s,y1s,x2s,y2s, wxs, wys);
  if(tid>=64 && tid<113)  subm[tid-64]  = subimap[(size_t)gp*49 + (tid-64)];
  if(tid>=128 && tid<177) objm[tid-128] = objimap[(size_t)gp*49 + (tid-128)];
  __syncthreads();
  if(tid<16){
    float o=0.f;
    #pragma unroll
    for(int p=0;p<7;p++) o += fabsf(wys[p][tid]);
    hmaskS[tid] = (o>0.f);
  } else if(tid>=32 && tid<38){
    int wc = tid-32; float o=0.f;
    #pragma unroll
    for(int q=0;q<7;q++)
      #pragma unroll
      for(int w=0;w<4;w++) o += fabsf(wxs[q][wc*4+w]);
    cmaskS[wc] = (o>0.f);
  }
  __syncthreads();
  float area = (x2s-x1s)*(y2s-y1s)/49.f;
  float sc = area>0.f ? 1.f/fmaxf(area,1e-9f) : 0.f;
  int c = tid;                          // rel channel 0..383
  const float* f = feats2T + (size_t)b*384*640 + 256 + c;
  float sq[49];
  #pragma unroll
  for(int s=0;s<49;s++) sq[s]=0.f;
  #pragma unroll
  for(int wc=0; wc<6; wc++){
    if(!cmaskS[wc]) continue;
    float tyv[7][4];
    #pragma unroll
    for(int p=0;p<7;p++)
      #pragma unroll
      for(int w=0;w<4;w++) tyv[p][w]=0.f;
    for(int h0=0; h0<16; h0+=4){
      float v[4][4];
      #pragma unroll
      for(int hh=0;hh<4;hh++){
        int h=h0+hh;
        if(hmaskS[h]){
          const float* fr = f + (size_t)(h*24 + wc*4)*640;
          #pragma unroll
          for(int w=0;w<4;w++) v[hh][w] = fr[(size_t)w*640];
        } else {
          #pragma unroll
          for(int w=0;w<4;w++) v[hh][w]=0.f;
        }
      }
      #pragma unroll
      for(int hh=0;hh<4;hh++){
        int h=h0+hh;
        #pragma unroll
        for(int p=0;p<7;p++){
          float wv = wys[p][h];
          #pragma unroll
          for(int w=0;w<4;w++) tyv[p][w] += wv*v[hh][w];
        }
      }
    }
    #pragma unroll
    for(int q=0;q<7;q++){
      #pragma unroll
      for(int p=0;p<7;p++){
        float d = 0.f;
        #pragma unroll
        for(int w=0;w<4;w++) d += wxs[q][wc*4+w]*tyv[p][w];
        sq[p*7+q] += d;
      }
    }
  }
  float* dst = pairA + (size_t)lp*49*384 + c;
  #pragma unroll
  for(int p=0;p<7;p++)
    #pragma unroll
    for(int q=0;q<7;q++){
      int s = p*7+q;
      float mlt = (c<128) ? 1.f : (c<256 ? subm[s] : objm[s]);
      dst[(size_t)s*384] = sq[s]*sc*mlt;
    }
}

// rel = relu(pairA @ W345 + A2[pair_i] + Bsum[pair_j] + brf).
// M = pairs*49 (multiple of 128), N=256, K=384. 128x128 tile, 8x8 per thread.
__global__ __launch_bounds__(256) void k_pairgemm(
  const float* __restrict__ A, const float* __restrict__ B,
  const float* __restrict__ A2, const float* __restrict__ Bsum,
  const float* __restrict__ brf, float* __restrict__ rel, int P0)
{
  __shared__ float As[32][128];
  __shared__ float Bs[32][128];
  int m0 = blockIdx.y*128, n0 = blockIdx.x*128;
  int tid = threadIdx.x, tx = tid&15, ty = tid>>4;
  float acc[8][8] = {};
  for(int k0=0;k0<384;k0+=32){
    {
      int m = tid & 127; int kk0 = (tid>>7)*16;
      const float* ap = A + (size_t)(m0+m)*384 + (k0+kk0);
      #pragma unroll
      for(int v=0;v<4;v++){
        float4 x = *(const float4*)(ap + v*4);
        As[kk0+v*4+0][m]=x.x; As[kk0+v*4+1][m]=x.y;
        As[kk0+v*4+2][m]=x.z; As[kk0+v*4+3][m]=x.w;
      }
    }
    {
      int n4 = (tid&31)*4; int kr = tid>>5;
      #pragma unroll
      for(int kk=kr; kk<32; kk+=8)
        *(float4*)&Bs[kk][n4] = *(const float4*)(B + (size_t)(k0+kk)*256 + n0 + n4);
    }
    __syncthreads();
    #pragma unroll
    for(int kk=0;kk<32;kk++){
      float av[8], bvv[8];
      *(float4*)&av[0] = *(const float4*)&As[kk][ty*8];
      *(float4*)&av[4] = *(const float4*)&As[kk][ty*8+4];
      *(float4*)&bvv[0] = *(const float4*)&Bs[kk][tx*4];
      *(float4*)&bvv[4] = *(const float4*)&Bs[kk][tx*4+64];
      #pragma unroll
      for(int i=0;i<8;i++)
        #pragma unroll
        for(int j=0;j<8;j++) acc[i][j] += av[i]*bvv[j];
    }
    __syncthreads();
  }
  #pragma unroll
  for(int r=0;r<8;r++){
    int row = m0 + ty*8 + r;
    unsigned pl = (unsigned)row / 49u;
    int s = row - (int)pl*49;
    int gp = P0 + (int)pl;
    int b2 = gp>>8, mm = gp&255, i = mm>>4, j = mm&15;
    const float* a2p = A2   + (((size_t)(b2*16+i)*49 + s)<<8);
    const float* bsp = Bsum + (((size_t)(b2*16+j)*49 + s)<<8);
    float* cp = rel + (((size_t)P0*49 + row)<<8);
    #pragma unroll
    for(int u=0;u<2;u++){
      int col = n0 + tx*4 + u*64;
      float4 bb = *(const float4*)(brf + col);
      float4 a2 = *(const float4*)(a2p + col);
      float4 bs = *(const float4*)(bsp + col);
      float4 o;
      o.x = fmaxf(acc[r][u*4+0] + bb.x + a2.x + bs.x, 0.f);
      o.y = fmaxf(acc[r][u*4+1] + bb.y + a2.y + bs.y, 0.f);
      o.z = fmaxf(acc[r][u*4+2] + bb.z + a2.z + bs.z, 0.f);
      o.w = fmaxf(acc[r][u*4+3] + bb.w + a2.w + bs.w, 0.f);
      *(float4*)(cp + col) = o;
    }
  }
}

// Sum split-K partials + bias, l2-normalize each 256-row, write output.
__global__ __launch_bounds__(256) void k_norm(const float* __restrict__ objp,
    const float* __restrict__ relp, const float* __restrict__ bofc,
    const float* __restrict__ brfc, float* __restrict__ out){
  __shared__ float red[4];
  int row = blockIdx.x, d = threadIdx.x;
  float v; float* dst;
  if(row < 128){
    v = bofc[d];
    for(int z=0;z<28;z++) v += objp[((size_t)z*128+row)*256 + d];
    dst = out + (size_t)row*256 + d;
  } else {
    int r = row-128;
    v = brfc[d];
    for(int z=0;z<28;z++) v += relp[((size_t)z*2048+r)*256 + d];
    dst = out + 32768 + (size_t)r*256 + d;
  }
  float s = v*v;
  #pragma unroll
  for(int off=1; off<64; off<<=1) s += __shfl_xor(s, off);
  if((d&63)==0) red[d>>6] = s;
  __syncthreads();
  float tot = red[0]+red[1]+red[2]+red[3];
  *dst = v / sqrtf(tot);
}

extern "C" void kernel_launch(void* const* d_in, const int* in_sizes, int n_in,
                              void* d_out, int out_size, void* d_ws, size_t ws_size,
                              hipStream_t stream){
  (void)in_sizes; (void)n_in; (void)out_size;
  const float* input = (const float*)d_in[0];
  const float* boxes = (const float*)d_in[1];
  const float* W_ctx = (const float*)d_in[3];  const float* b_ctx = (const float*)d_in[4];
  const float* W_rel = (const float*)d_in[5];  const float* b_rel = (const float*)d_in[6];
  const float* W_of  = (const float*)d_in[7];  const float* b_of  = (const float*)d_in[8];
  const float* W_rf  = (const float*)d_in[9];  const float* b_rf  = (const float*)d_in[10];
  const float* W_ofc = (const float*)d_in[11]; const float* b_ofc = (const float*)d_in[12];
  const float* W_rfc = (const float*)d_in[13]; const float* b_rfc = (const float*)d_in[14];
  float* ws = (float*)d_ws;

  float* featT   = ws + 0;         // 786432   [b][pix384][c256]
  float* feats2T = ws + 786432;    // 1966080  [b][pix384][c640] (ctx 0..255, rel 256..639)
  float* W2T     = ws + 2752512;   // 163840   [c256][o640] (ctx|rel interleaved)
  float* WofT    = ws + 2916352;   // 131072   [c512][o256]
  float* WrfT    = ws + 3047424;   // 229376   [c896][o256]
  float* WofcT   = ws + 3276800;   // 3211264  [k12544][d256]
  float* WrfcT   = ws + 6488064;   // 3211264
  float* ctxpool = ws + 9699328;   // 100352   [b][s49][c256]
  float* inbuf   = ws + 9799680;   // 3211264  [b][n][s49][c512]
  float* obj     = ws + 13010944;  // 1605632  [b][n][s49][o256]  (pre-relu)
  float* A2b     = ws + 14616576;  // 1605632  [b][i][s][o] = obj @ WrfT[0:256]
  float* Bsb     = ws + 16222208;  // 1605632  [b][j][s][o] = obj @ WrfT[256:512] (adjacent!)
  float* unions  = ws + 17827840;  // 8192
  float* boximap = ws + 17836032;  // 6272
  float* subimap = ws + 17842304;  // 100352
  float* objimap = ws + 17942656;  // 100352
  float* rel     = ws + 18043008;  // 25690112 [b][m256][s49][o256], relu'd
  float* objfcp  = ws + 43733120;  // 917504   28 x (128x256) split-K partials
  float* relfcp  = ws + 44650624;  // 14680064 28 x (2048x256) split-K partials
  float* bias640 = ws + 59330688;  // 640
  float* pairA   = ws + 59331328;  // up to 38535168 extra if ws allows (chunked)

  // pick pair-chunking so pairA fits the provided workspace
  size_t wsfloats = ws_size / 4;
  int NCH = 0;
  for(int c=1; c<=16; c<<=1){
    if(59331328ull + (size_t)(2048/c)*49*384 <= wsfloats){ NCH = c; break; }
  }
  if(NCH == 0){
    // Safe fallback: alias pairA into the objfcp/relfcp region (15,597,568
    // floats, dead until after the pair loop). NCH=16 chunk needs 2,408,448.
    NCH = 16;
    pairA = objfcp;
  }
  int PPC = 2048/NCH;                  // pairs per chunk (>=128, multiple of 128)

  dim3 tb(32,8);
  k_transpose<<<dim3(12,8,8),  tb, 0, stream>>>(input, featT, 256, 384, 256, 0);
  k_transpose<<<dim3(8,8,1),   tb, 0, stream>>>(W_ctx, W2T,   256, 256, 640, 0);
  k_transpose<<<dim3(8,12,1),  tb, 0, stream>>>(W_rel, W2T,   384, 256, 640, 256);
  k_transpose<<<dim3(16,8,1),  tb, 0, stream>>>(W_of,  WofT,  256, 512, 256, 0);
  k_transpose<<<dim3(28,8,1),  tb, 0, stream>>>(W_rf,  WrfT,  256, 896, 256, 0);
  k_transpose<<<dim3(392,8,1), tb, 0, stream>>>(W_ofc, WofcT, 256, 12544, 256, 0);
  k_transpose<<<dim3(392,8,1), tb, 0, stream>>>(W_rfc, WrfcT, 256, 12544, 256, 0);
  k_bias640<<<3, 256, 0, stream>>>(b_ctx, b_rel, bias640);

  // merged conv1x1 (ctx|rel): feats2T[b] = featT[b] @ W2T + bias640
  k_gemm<64,64,4,4><<<dim3(10,6,8), 256, 0, stream>>>(featT,256,98304LL, W2T,640, bias640,
                                          feats2T,640,245760LL, 256,0,0);

  k_imap<<<8, 256, 0, stream>>>(boxes, unions, boximap, subimap, objimap);
  k_ctxpool<<<8, 256, 0, stream>>>(feats2T, ctxpool);
  k_objpool<<<128, 256, 0, stream>>>(boxes, featT, ctxpool, boximap, inbuf);

  // obj = inbuf @ WofT + b_of    (M=6272,N=256,K=512)
  k_gemm<64,64,4,4><<<dim3(4,98,1), 256, 0, stream>>>(inbuf,512,0LL, WofT,256, b_of,
                                           obj,256,0LL, 512,0,0);
  // A2 = obj @ WrfT[0:256] (z=0), Bsum = obj @ WrfT[256:512] (z=1, kBase=256)
  k_gemm<64,64,4,4><<<dim3(4,98,2), 256, 0, stream>>>(obj,256,0LL, WrfT,256, nullptr,
                                           A2b,256,1605632LL, 256,256,0);

  // rel path: pool pairs -> one big GEMM with fused epilogue, chunked over pairs
  for(int ch=0; ch<NCH; ch++){
    int P0 = ch*PPC;
    k_poolpairs<<<PPC, 384, 0, stream>>>(feats2T, unions, subimap, objimap, pairA, P0);
    k_pairgemm<<<dim3(2, PPC*49/128), 256, 0, stream>>>(pairA, WrfT+512*256,
                                           A2b, Bsb, b_rf, rel, P0);
  }

  // obj fc: split-K 28 (Kchunk 448), relu(A) + permuted B rows (flags=3)
  k_gemm<64,64,4,4><<<dim3(4,2,28),  256, 0, stream>>>(obj,12544,448LL, WofcT,256, nullptr,
                                           objfcp,256,32768LL, 448,448,3);
  // rel fc: 128x128 tile, split-K 28 (Kchunk 448), permuted B rows
  k_gemm<128,128,8,8><<<dim3(2,16,28), 256, 0, stream>>>(rel,12544,448LL, WrfcT,256, nullptr,
                                           relfcp,256,524288LL, 448,448,2);

  k_norm<<<2176, 256, 0, stream>>>(objfcp, relfcp, b_ofc, b_rfc, (float*)d_out);
}

// Round 10
// 1268.257 us; speedup vs baseline: 1.3649x; 1.3649x over previous
//
#include <hip/hip_runtime.h>
#include <cstddef>

#define SCALE (1.0f/16.0f)

__device__ __forceinline__ float hatG(float t){
  float tl = fminf(fmaxf(t,-1.f),0.f);
  float tr = fminf(fmaxf(t,0.f),1.f);
  return 0.5f*(tl+1.f)*(tl+1.f) + 0.5f - 0.5f*(1.f-tr)*(1.f-tr);
}

// dst[c*ldd + off + r] = src[r*cols + c]; batched via blockIdx.z
__global__ __launch_bounds__(256) void k_transpose(const float* __restrict__ src,
    float* __restrict__ dst, int rows, int cols, int ldd, int off){
  __shared__ float tile[32][33];
  src += (size_t)blockIdx.z * rows * cols;
  dst += (size_t)blockIdx.z * cols * ldd;
  int c0 = blockIdx.x*32, r0 = blockIdx.y*32;
  int tx = threadIdx.x, ty = threadIdx.y;
  for(int i=ty;i<32;i+=8){
    int r=r0+i, c=c0+tx;
    if(r<rows && c<cols) tile[i][tx] = src[(size_t)r*cols + c];
  }
  __syncthreads();
  for(int i=ty;i<32;i+=8){
    int c=c0+i, r=r0+tx;
    if(c<cols && r<rows) dst[(size_t)c*ldd + off + r] = tile[tx][i];
  }
}

__global__ void k_bias640(const float* __restrict__ a, const float* __restrict__ b,
                          float* __restrict__ o){
  int i = threadIdx.x + blockIdx.x*256;
  if(i<256) o[i]=a[i];
  else if(i<640) o[i]=b[i-256];
}

__device__ void imap_one(float ix1,float iy1,float ix2,float iy2,
                         float ax1,float ay1,float ax2,float ay2,
                         float* __restrict__ out){
  float ch = fmaxf((ay2-ay1)/7.f, 1e-9f);
  float cw = fmaxf((ax2-ax1)/7.f, 1e-9f);
  float oy[7], ox[7];
  #pragma unroll
  for(int p=0;p<7;p++){
    float e0 = ay1 + (ay2-ay1)*((float)p/7.f);
    float e1 = ay1 + (ay2-ay1)*((float)(p+1)/7.f);
    oy[p] = fmaxf(fminf(e1, iy2) - fmaxf(e0, iy1), 0.f) / ch;
  }
  #pragma unroll
  for(int q=0;q<7;q++){
    float e0 = ax1 + (ax2-ax1)*((float)q/7.f);
    float e1 = ax1 + (ax2-ax1)*((float)(q+1)/7.f);
    ox[q] = fmaxf(fminf(e1, ix2) - fmaxf(e0, ix1), 0.f) / cw;
  }
  for(int p=0;p<7;p++)
    for(int q=0;q<7;q++) out[p*7+q] = oy[p]*ox[q];
}

__global__ __launch_bounds__(256) void k_imap(const float* __restrict__ boxes,
  float* __restrict__ unions, float* __restrict__ boximap,
  float* __restrict__ subimap, float* __restrict__ objimap){
  int b = blockIdx.x, m = threadIdx.x;
  const float* bx = boxes + (size_t)b*16*4;
  int i = m>>4, j = m&15;              // sub = repeat -> i, obj = tile -> j
  float sx1=bx[i*4+0], sy1=bx[i*4+1], sx2=bx[i*4+2], sy2=bx[i*4+3];
  float ox1=bx[j*4+0], oy1=bx[j*4+1], ox2=bx[j*4+2], oy2=bx[j*4+3];
  float ux1=fminf(sx1,ox1), uy1=fminf(sy1,oy1);
  float ux2=fmaxf(sx2,ox2), uy2=fmaxf(sy2,oy2);
  float* up = unions + ((size_t)b*256+m)*4;
  up[0]=ux1; up[1]=uy1; up[2]=ux2; up[3]=uy2;
  imap_one(sx1,sy1,sx2,sy2, ux1,uy1,ux2,uy2, subimap + ((size_t)b*256+m)*49);
  imap_one(ox1,oy1,ox2,oy2, ux1,uy1,ux2,uy2, objimap + ((size_t)b*256+m)*49);
  if(m<16){
    imap_one(bx[m*4+0],bx[m*4+1],bx[m*4+2],bx[m*4+3],
             0.f,0.f,384.f,256.f, boximap + ((size_t)b*16+m)*49);
  }
}

// PrRoI bin weights in SCALED feature coords (box already * SCALE).
__device__ __forceinline__ void build_weights(int tid, float x1s,float y1s,float x2s,float y2s,
                              float (*wxs)[24], float (*wys)[16]){
  if(tid<7){
    int q=tid;
    float e0 = x1s + (x2s-x1s)*((float)q/7.f);
    float e1 = x1s + (x2s-x1s)*((float)(q+1)/7.f);
    for(int i2=0;i2<24;i2++) wxs[q][i2] = hatG(e1-(float)i2)-hatG(e0-(float)i2);
  } else if(tid>=16 && tid<23){
    int p=tid-16;
    float e0 = y1s + (y2s-y1s)*((float)p/7.f);
    float e1 = y1s + (y2s-y1s)*((float)(p+1)/7.f);
    for(int i2=0;i2<16;i2++) wys[p][i2] = hatG(e1-(float)i2)-hatG(e0-(float)i2);
  }
}

// Pool ctx channels (0..255 of feats2T) with the full-image box.
// One block per (b, s=p*7+q): 392 blocks, 256 threads (one per channel).
__global__ __launch_bounds__(256) void k_ctxpool(const float* __restrict__ feats2T,
                                                 float* __restrict__ ctxpool){
  int b = blockIdx.x, s = blockIdx.y;
  int p = s/7, q = s-p*7;
  int c = threadIdx.x;
  float y0 = 16.f*(float)p/7.f,  y1 = 16.f*(float)(p+1)/7.f;
  float x0 = 24.f*(float)q/7.f,  x1 = 24.f*(float)(q+1)/7.f;
  float wx[24];
  #pragma unroll
  for(int w=0;w<24;w++) wx[w] = hatG(x1-(float)w)-hatG(x0-(float)w);
  const float* f = feats2T + (size_t)b*384*640 + c;
  float acc = 0.f;
  for(int h=0;h<16;h++){
    float wy = hatG(y1-(float)h)-hatG(y0-(float)h);
    if(wy==0.f) continue;                        // wave-uniform
    const float* fr = f + (size_t)(h*24)*640;
    #pragma unroll
    for(int w=0;w<24;w++){
      if(wx[w]!=0.f) acc += wy*wx[w]*fr[(size_t)w*640];
    }
  }
  ctxpool[((size_t)b*49+s)*256 + c] = acc * (49.f/(24.f*16.f));
}

// Pool feat with obj boxes, write fused-input rows: inbuf[b][n][s][c512]
__global__ __launch_bounds__(256) void k_objpool(const float* __restrict__ boxes,
    const float* __restrict__ featT, const float* __restrict__ ctxpool,
    const float* __restrict__ boximap, float* __restrict__ inbuf){
  __shared__ float wxs[7][24];
  __shared__ float wys[7][16];
  int blk = blockIdx.x; int b = blk>>4, n = blk&15; int tid = threadIdx.x;
  const float* bx = boxes + ((size_t)b*16+n)*4;
  float x1s=bx[0]*SCALE, y1s=bx[1]*SCALE, x2s=bx[2]*SCALE, y2s=bx[3]*SCALE;
  build_weights(tid, x1s,y1s,x2s,y2s, wxs, wys);
  __syncthreads();
  float area = (x2s-x1s)*(y2s-y1s)/49.f;
  float sc = area>0.f ? 1.f/fmaxf(area,1e-9f) : 0.f;
  int c = tid;
  const float* f = featT + (size_t)b*384*256 + c;
  float* ob = inbuf + (size_t)(b*16+n)*49*512;
  for(int p=0;p<7;p++){
    float tyv[24];
    #pragma unroll
    for(int w=0;w<24;w++) tyv[w]=0.f;
    for(int h=0;h<16;h++){
      float wv = wys[p][h];
      if(wv==0.f) continue;
      const float* fr = f + (size_t)(h*24)*256;
      #pragma unroll
      for(int w=0;w<24;w++) tyv[w] += wv*fr[(size_t)w*256];
    }
    for(int q=0;q<7;q++){
      float s=0.f;
      #pragma unroll
      for(int w=0;w<24;w++) s += wxs[q][w]*tyv[w];
      ob[(size_t)(p*7+q)*512 + c] = s*sc;
    }
  }
  // concat channels 256..511: x (ctx 0..127), y*box_imap (ctx 128..255)
  const float* cp = ctxpool + (size_t)b*49*256;
  for(int s=0;s<49;s++){
    float bi = boximap[((size_t)b*16+n)*49 + s];
    if(tid<128) ob[(size_t)s*512 + 256 + tid] = cp[(size_t)s*256 + tid];
    else        ob[(size_t)s*512 + 384 + (tid-128)] = cp[(size_t)s*256 + 128 + (tid-128)] * bi;
  }
}

// Tiled fp32 GEMM: C[M,N] = A[M,K] * B[K,N] (+bias). flags: 1=reluA, 2=permB.
// grid.z batches (aZ/cZ strides) and doubles as split-K / B-row-window (kBasePerZ).
// 256 threads. Requires M%BM==0, N%BN==0, Kchunk%32==0, float4 alignment.
template<int BM,int BN,int TM,int TN>
__global__ __launch_bounds__(256) void k_gemm(
    const float* __restrict__ A, int lda, long long aZ,
    const float* __restrict__ B, int ldb,
    const float* __restrict__ bias,
    float* __restrict__ C, int ldc, long long cZ,
    int Kchunk, int kBasePerZ, int flags)
{
  static_assert((BM/TM)*(BN/TN)==256 && BN/TN==16, "layout");
  int z = blockIdx.z;
  A += (size_t)z*aZ; C += (size_t)z*cZ;
  int kBase = z*kBasePerZ;
  int m0 = blockIdx.y*BM, n0 = blockIdx.x*BN;
  __shared__ float As[32][BM];
  __shared__ float Bs[32][BN];
  int tid = threadIdx.x, tx = tid&15, ty = tid>>4;
  float acc[TM][TN] = {};
  constexpr int AV = BM/32;          // float4s per thread for A stage
  constexpr int NB4 = BN/4;          // float4 columns in B stage
  constexpr int KSTEP = 256/NB4;     // k-rows stride in B stage
  constexpr int TM4 = TM/4, TN4 = TN/4;
  for(int k0=0;k0<Kchunk;k0+=32){
    {
      int m = tid % BM; int kk0 = (tid / BM) * (AV*4);
      const float* ap = A + (size_t)(m0+m)*lda + (k0+kk0);
      #pragma unroll
      for(int v=0;v<AV;v++){
        float4 x = *(const float4*)(ap + v*4);
        if(flags&1){
          x.x=fmaxf(x.x,0.f); x.y=fmaxf(x.y,0.f); x.z=fmaxf(x.z,0.f); x.w=fmaxf(x.w,0.f);
        }
        As[kk0+v*4+0][m]=x.x; As[kk0+v*4+1][m]=x.y;
        As[kk0+v*4+2][m]=x.z; As[kk0+v*4+3][m]=x.w;
      }
    }
    {
      int n4 = (tid % NB4)*4; int kr = tid / NB4;
      #pragma unroll
      for(int kk=kr; kk<32; kk+=KSTEP){
        int kg = kBase + k0 + kk;
        int src = (flags&2) ? ((kg&255)*49 + (kg>>8)) : kg;  // K perm: ours s*256+c -> ref c*49+s
        *(float4*)&Bs[kk][n4] = *(const float4*)(B + (size_t)src*ldb + n0 + n4);
      }
    }
    __syncthreads();
    #pragma unroll
    for(int kk=0;kk<32;kk++){
      float av[TM], bvv[TN];
      #pragma unroll
      for(int v=0;v<TM4;v++) *(float4*)&av[v*4]  = *(const float4*)&As[kk][ty*TM + v*4];
      #pragma unroll
      for(int u=0;u<TN4;u++) *(float4*)&bvv[u*4] = *(const float4*)&Bs[kk][tx*4 + u*64];
      #pragma unroll
      for(int i=0;i<TM;i++)
        #pragma unroll
        for(int j=0;j<TN;j++) acc[i][j] += av[i]*bvv[j];
    }
    __syncthreads();
  }
  float bb[TN];
  #pragma unroll
  for(int u=0;u<TN4;u++){
    float4 v = make_float4(0.f,0.f,0.f,0.f);
    if(bias) v = *(const float4*)(bias + n0 + tx*4 + u*64);
    bb[u*4+0]=v.x; bb[u*4+1]=v.y; bb[u*4+2]=v.z; bb[u*4+3]=v.w;
  }
  #pragma unroll
  for(int r=0;r<TM;r++){
    #pragma unroll
    for(int u=0;u<TN4;u++){
      float4 o;
      o.x = acc[r][u*4+0]+bb[u*4+0]; o.y = acc[r][u*4+1]+bb[u*4+1];
      o.z = acc[r][u*4+2]+bb[u*4+2]; o.w = acc[r][u*4+3]+bb[u*4+3];
      *(float4*)(C + (size_t)(m0+ty*TM+r)*ldc + n0 + tx*4 + u*64) = o;
    }
  }
}

// Per-pair prroi-pool of rel_feat over union box, modulated by imaps, written
// as GEMM-ready rows: pairA[(lp*49+s)*384 + c] for lp in this chunk.
__global__ __launch_bounds__(384) void k_poolpairs(
  const float* __restrict__ feats2T, const float* __restrict__ unions,
  const float* __restrict__ subimap, const float* __restrict__ objimap,
  float* __restrict__ pairA, int P0)
{
  __shared__ float wxs[7][24];
  __shared__ float wys[7][16];
  __shared__ float subm[49];
  __shared__ float objm[49];
  __shared__ int hmaskS[16];            // any wys[p][h] != 0
  __shared__ int cmaskS[8];             // any wxs[q][wc*4..wc*4+3] != 0
  int lp = blockIdx.x; int gp = P0 + lp; int b = gp>>8; int tid = threadIdx.x;
  const float* u = unions + (size_t)gp*4;
  float x1s=u[0]*SCALE, y1s=u[1]*SCALE, x2s=u[2]*SCALE, y2s=u[3]*SCALE;
  build_weights(tid, x1s,y1s,x2s,y2s, wxs, wys);
  if(tid>=64 && tid<113)  subm[tid-64]  = subimap[(size_t)gp*49 + (tid-64)];
  if(tid>=128 && tid<177) objm[tid-128] = objimap[(size_t)gp*49 + (tid-128)];
  __syncthreads();
  if(tid<16){
    float o=0.f;
    #pragma unroll
    for(int p=0;p<7;p++) o += fabsf(wys[p][tid]);
    hmaskS[tid] = (o>0.f);
  } else if(tid>=32 && tid<38){
    int wc = tid-32; float o=0.f;
    #pragma unroll
    for(int q=0;q<7;q++)
      #pragma unroll
      for(int w=0;w<4;w++) o += fabsf(wxs[q][wc*4+w]);
    cmaskS[wc] = (o>0.f);
  }
  __syncthreads();
  float area = (x2s-x1s)*(y2s-y1s)/49.f;
  float sc = area>0.f ? 1.f/fmaxf(area,1e-9f) : 0.f;
  int c = tid;                          // rel channel 0..383
  const float* f = feats2T + (size_t)b*384*640 + 256 + c;
  float sq[49];
  #pragma unroll
  for(int s=0;s<49;s++) sq[s]=0.f;
  #pragma unroll
  for(int wc=0; wc<6; wc++){
    if(!cmaskS[wc]) continue;
    float tyv[7][4];
    #pragma unroll
    for(int p=0;p<7;p++)
      #pragma unroll
      for(int w=0;w<4;w++) tyv[p][w]=0.f;
    for(int h0=0; h0<16; h0+=4){
      float v[4][4];
      #pragma unroll
      for(int hh=0;hh<4;hh++){
        int h=h0+hh;
        if(hmaskS[h]){
          const float* fr = f + (size_t)(h*24 + wc*4)*640;
          #pragma unroll
          for(int w=0;w<4;w++) v[hh][w] = fr[(size_t)w*640];
        } else {
          #pragma unroll
          for(int w=0;w<4;w++) v[hh][w]=0.f;
        }
      }
      #pragma unroll
      for(int hh=0;hh<4;hh++){
        int h=h0+hh;
        #pragma unroll
        for(int p=0;p<7;p++){
          float wv = wys[p][h];
          #pragma unroll
          for(int w=0;w<4;w++) tyv[p][w] += wv*v[hh][w];
        }
      }
    }
    #pragma unroll
    for(int q=0;q<7;q++){
      #pragma unroll
      for(int p=0;p<7;p++){
        float d = 0.f;
        #pragma unroll
        for(int w=0;w<4;w++) d += wxs[q][wc*4+w]*tyv[p][w];
        sq[p*7+q] += d;
      }
    }
  }
  float* dst = pairA + (size_t)lp*49*384 + c;
  #pragma unroll
  for(int p=0;p<7;p++)
    #pragma unroll
    for(int q=0;q<7;q++){
      int s = p*7+q;
      float mlt = (c<128) ? 1.f : (c<256 ? subm[s] : objm[s]);
      dst[(size_t)s*384] = sq[s]*sc*mlt;
    }
}

// rel = relu(pairA @ W345 + A2[pair_i] + Bsum[pair_j] + brf).
// M = pairs*49 (multiple of 128), N=256, K=384. 128x128 tile, 8x8 per thread.
__global__ __launch_bounds__(256) void k_pairgemm(
  const float* __restrict__ A, const float* __restrict__ B,
  const float* __restrict__ A2, const float* __restrict__ Bsum,
  const float* __restrict__ brf, float* __restrict__ rel, int P0)
{
  __shared__ float As[32][128];
  __shared__ float Bs[32][128];
  int m0 = blockIdx.y*128, n0 = blockIdx.x*128;
  int tid = threadIdx.x, tx = tid&15, ty = tid>>4;
  float acc[8][8] = {};
  for(int k0=0;k0<384;k0+=32){
    {
      int m = tid & 127; int kk0 = (tid>>7)*16;
      const float* ap = A + (size_t)(m0+m)*384 + (k0+kk0);
      #pragma unroll
      for(int v=0;v<4;v++){
        float4 x = *(const float4*)(ap + v*4);
        As[kk0+v*4+0][m]=x.x; As[kk0+v*4+1][m]=x.y;
        As[kk0+v*4+2][m]=x.z; As[kk0+v*4+3][m]=x.w;
      }
    }
    {
      int n4 = (tid&31)*4; int kr = tid>>5;
      #pragma unroll
      for(int kk=kr; kk<32; kk+=8)
        *(float4*)&Bs[kk][n4] = *(const float4*)(B + (size_t)(k0+kk)*256 + n0 + n4);
    }
    __syncthreads();
    #pragma unroll
    for(int kk=0;kk<32;kk++){
      float av[8], bvv[8];
      *(float4*)&av[0] = *(const float4*)&As[kk][ty*8];
      *(float4*)&av[4] = *(const float4*)&As[kk][ty*8+4];
      *(float4*)&bvv[0] = *(const float4*)&Bs[kk][tx*4];
      *(float4*)&bvv[4] = *(const float4*)&Bs[kk][tx*4+64];
      #pragma unroll
      for(int i=0;i<8;i++)
        #pragma unroll
        for(int j=0;j<8;j++) acc[i][j] += av[i]*bvv[j];
    }
    __syncthreads();
  }
  #pragma unroll
  for(int r=0;r<8;r++){
    int row = m0 + ty*8 + r;
    unsigned pl = (unsigned)row / 49u;
    int s = row - (int)pl*49;
    int gp = P0 + (int)pl;
    int b2 = gp>>8, mm = gp&255, i = mm>>4, j = mm&15;
    const float* a2p = A2   + (((size_t)(b2*16+i)*49 + s)<<8);
    const float* bsp = Bsum + (((size_t)(b2*16+j)*49 + s)<<8);
    float* cp = rel + (((size_t)P0*49 + row)<<8);
    #pragma unroll
    for(int u=0;u<2;u++){
      int col = n0 + tx*4 + u*64;
      float4 bb = *(const float4*)(brf + col);
      float4 a2 = *(const float4*)(a2p + col);
      float4 bs = *(const float4*)(bsp + col);
      float4 o;
      o.x = fmaxf(acc[r][u*4+0] + bb.x + a2.x + bs.x, 0.f);
      o.y = fmaxf(acc[r][u*4+1] + bb.y + a2.y + bs.y, 0.f);
      o.z = fmaxf(acc[r][u*4+2] + bb.z + a2.z + bs.z, 0.f);
      o.w = fmaxf(acc[r][u*4+3] + bb.w + a2.w + bs.w, 0.f);
      *(float4*)(cp + col) = o;
    }
  }
}

// Sum split-K partials + bias, l2-normalize each 256-row, write output.
__global__ __launch_bounds__(256) void k_norm(const float* __restrict__ objp,
    const float* __restrict__ relp, const float* __restrict__ bofc,
    const float* __restrict__ brfc, float* __restrict__ out){
  __shared__ float red[4];
  int row = blockIdx.x, d = threadIdx.x;
  float v; float* dst;
  if(row < 128){
    v = bofc[d];
    for(int z=0;z<28;z++) v += objp[((size_t)z*128+row)*256 + d];
    dst = out + (size_t)row*256 + d;
  } else {
    int r = row-128;
    v = brfc[d];
    for(int z=0;z<28;z++) v += relp[((size_t)z*2048+r)*256 + d];
    dst = out + 32768 + (size_t)r*256 + d;
  }
  float s = v*v;
  #pragma unroll
  for(int off=1; off<64; off<<=1) s += __shfl_xor(s, off);
  if((d&63)==0) red[d>>6] = s;
  __syncthreads();
  float tot = red[0]+red[1]+red[2]+red[3];
  *dst = v / sqrtf(tot);
}

extern "C" void kernel_launch(void* const* d_in, const int* in_sizes, int n_in,
                              void* d_out, int out_size, void* d_ws, size_t ws_size,
                              hipStream_t stream){
  (void)in_sizes; (void)n_in; (void)out_size;
  const float* input = (const float*)d_in[0];
  const float* boxes = (const float*)d_in[1];
  const float* W_ctx = (const float*)d_in[3];  const float* b_ctx = (const float*)d_in[4];
  const float* W_rel = (const float*)d_in[5];  const float* b_rel = (const float*)d_in[6];
  const float* W_of  = (const float*)d_in[7];  const float* b_of  = (const float*)d_in[8];
  const float* W_rf  = (const float*)d_in[9];  const float* b_rf  = (const float*)d_in[10];
  const float* W_ofc = (const float*)d_in[11]; const float* b_ofc = (const float*)d_in[12];
  const float* W_rfc = (const float*)d_in[13]; const float* b_rfc = (const float*)d_in[14];
  float* ws = (float*)d_ws;

  float* featT   = ws + 0;         // 786432   [b][pix384][c256]
  float* feats2T = ws + 786432;    // 1966080  [b][pix384][c640] (ctx 0..255, rel 256..639)
  float* W2T     = ws + 2752512;   // 163840   [c256][o640] (ctx|rel interleaved)
  float* WofT    = ws + 2916352;   // 131072   [c512][o256]
  float* WrfT    = ws + 3047424;   // 229376   [c896][o256]
  float* WofcT   = ws + 3276800;   // 3211264  [k12544][d256]
  float* WrfcT   = ws + 6488064;   // 3211264
  float* ctxpool = ws + 9699328;   // 100352   [b][s49][c256]
  float* inbuf   = ws + 9799680;   // 3211264  [b][n][s49][c512]
  float* obj     = ws + 13010944;  // 1605632  [b][n][s49][o256]  (pre-relu)
  float* A2b     = ws + 14616576;  // 1605632  [b][i][s][o] = obj @ WrfT[0:256]
  float* Bsb     = ws + 16222208;  // 1605632  [b][j][s][o] = obj @ WrfT[256:512] (adjacent!)
  float* unions  = ws + 17827840;  // 8192
  float* boximap = ws + 17836032;  // 6272
  float* subimap = ws + 17842304;  // 100352
  float* objimap = ws + 17942656;  // 100352
  float* rel     = ws + 18043008;  // 25690112 [b][m256][s49][o256], relu'd
  float* objfcp  = ws + 43733120;  // 917504   28 x (128x256) split-K partials
  float* relfcp  = ws + 44650624;  // 14680064 28 x (2048x256) split-K partials
  float* bias640 = ws + 59330688;  // 640
  float* pairA   = ws + 59331328;  // tail (used only if ws_size allows)

  // pick pair-chunking; prefer tail, else alias the (currently dead) FC region
  size_t wsfloats = ws_size / 4;
  int NCH = 0;
  for(int c2=1; c2<=4; c2<<=1){
    if(59331328ull + (size_t)(2048/c2)*49*384 <= wsfloats){ NCH = c2; break; }
  }
  if(NCH == 0){
    // objfcp+relfcp region = 15,597,568 floats, dead until after the pair
    // loop; NCH=4 chunk needs 9,633,792 floats -> guaranteed fit.
    NCH = 4;
    pairA = objfcp;
  }
  int PPC = 2048/NCH;                  // pairs per chunk; PPC*49 % 128 == 0

  dim3 tb(32,8);
  k_transpose<<<dim3(12,8,8),  tb, 0, stream>>>(input, featT, 256, 384, 256, 0);
  k_transpose<<<dim3(8,8,1),   tb, 0, stream>>>(W_ctx, W2T,   256, 256, 640, 0);
  k_transpose<<<dim3(8,12,1),  tb, 0, stream>>>(W_rel, W2T,   384, 256, 640, 256);
  k_transpose<<<dim3(16,8,1),  tb, 0, stream>>>(W_of,  WofT,  256, 512, 256, 0);
  k_transpose<<<dim3(28,8,1),  tb, 0, stream>>>(W_rf,  WrfT,  256, 896, 256, 0);
  k_transpose<<<dim3(392,8,1), tb, 0, stream>>>(W_ofc, WofcT, 256, 12544, 256, 0);
  k_transpose<<<dim3(392,8,1), tb, 0, stream>>>(W_rfc, WrfcT, 256, 12544, 256, 0);
  k_bias640<<<3, 256, 0, stream>>>(b_ctx, b_rel, bias640);

  // merged conv1x1 (ctx|rel): feats2T[b] = featT[b] @ W2T + bias640
  k_gemm<64,64,4,4><<<dim3(10,6,8), 256, 0, stream>>>(featT,256,98304LL, W2T,640, bias640,
                                          feats2T,640,245760LL, 256,0,0);

  k_imap<<<8, 256, 0, stream>>>(boxes, unions, boximap, subimap, objimap);
  k_ctxpool<<<dim3(8,49), 256, 0, stream>>>(feats2T, ctxpool);
  k_objpool<<<128, 256, 0, stream>>>(boxes, featT, ctxpool, boximap, inbuf);

  // obj = inbuf @ WofT + b_of    (M=6272,N=256,K=512)
  k_gemm<64,64,4,4><<<dim3(4,98,1), 256, 0, stream>>>(inbuf,512,0LL, WofT,256, b_of,
                                           obj,256,0LL, 512,0,0);
  // A2 = obj @ WrfT[0:256] (z=0), Bsum = obj @ WrfT[256:512] (z=1, kBase=256)
  k_gemm<64,64,4,4><<<dim3(4,98,2), 256, 0, stream>>>(obj,256,0LL, WrfT,256, nullptr,
                                           A2b,256,1605632LL, 256,256,0);

  // rel path: pool pairs -> one big GEMM with fused epilogue, chunked over pairs
  for(int ch=0; ch<NCH; ch++){
    int P0 = ch*PPC;
    k_poolpairs<<<PPC, 384, 0, stream>>>(feats2T, unions, subimap, objimap, pairA, P0);
    k_pairgemm<<<dim3(2, PPC*49/128), 256, 0, stream>>>(pairA, WrfT+512*256,
                                           A2b, Bsb, b_rf, rel, P0);
  }

  // obj fc: split-K 28 (Kchunk 448), relu(A) + permuted B rows (flags=3)
  k_gemm<64,64,4,4><<<dim3(4,2,28),  256, 0, stream>>>(obj,12544,448LL, WofcT,256, nullptr,
                                           objfcp,256,32768LL, 448,448,3);
  // rel fc: 128x128 tile, split-K 28 (Kchunk 448), permuted B rows
  k_gemm<128,128,8,8><<<dim3(2,16,28), 256, 0, stream>>>(rel,12544,448LL, WrfcT,256, nullptr,
                                           relfcp,256,524288LL, 448,448,2);

  k_norm<<<2176, 256, 0, stream>>>(objfcp, relfcp, b_ofc, b_rfc, (float*)d_out);
}